// Round 19
// baseline (491.665 us; speedup 1.0000x reference)
//
#include <hip/hip_runtime.h>
#include <hip/hip_bf16.h>
#include <stdint.h>

// DenseGraphAttentionHead N=8192, IN=512, OUT=256, ~50% dense int32 mask.
//
// Pipeline:
//   k_convert_w : W f32 -> bf16 chunked (16B chunk (kb,row) at kb*2048+row*8).
//   k_front     : FUSED k_mask + k_wh (bid%9==8 -> wh). mask: int32 ->
//                 bitmask bm[row][wj] via __ballot (coalesced stream). wh:
//                 Wh = nodes@W^T + b (mfma) -> WhL chunked bf16 + tables.
//                 MAX-IDENTITY (exact): exp(lrelu(s1+s2)) = max(e^{s1}e^{s2},
//                 e^{.2s1}e^{.2s2}).
//                 sAC = [A=e^{s1} | C=e^{.2s1}] f32;
//                 sPK[j] = u32 {bf16 B=e^{s2} hi | bf16 D=e^{.2s2} lo}.
//   k_attn      : WAVE-PRIVATE masked-softmax @ Wh: ZERO LDS, ZERO barriers.
//                 R12's idea with the register budget fixed: wave = 32 rows x
//                 64 cols -> acc only 32 regs; ~96 VGPRs left for an explicit
//                 2-deep register pipeline (named Win structs, static idx).
//                 Per window per wave EXACTLY 8 loads {4 B-frag dwordx4 (L2-
//                 resident chunked WhL), 2 PK dwordx4 (broadcast), 2 bm
//                 dwords}; ping-pong WA/WB with counted s_waitcnt vmcnt(8)
//                 (drains the older window only; never 0). Waves free-run --
//                 wave-slip hides L2 latency, which the barrier'd designs
//                 (R6-R18, all ~100us) structurally forbade.
//                 Block 512 thr = 2 rowgroups(32) x 4 colquarters(64);
//                 grid 128rt x 8jc = 1024 blocks = 2/CU, 16 waves/CU.
//   k_comb      : out = sum_jc(pnum) / sum_jc(pden), 8 partials.
//
// MFMA conventions (verified R1-R18 on this problem):
//   A frag: lane&15 = m, k = (lane>>4)*8 + i ; B same per-lane k order
//   D: col = lane&15, row = (lane>>4)*4 + reg

#define NN 8192
#define IND 512
#define OUTD 256

typedef __attribute__((ext_vector_type(8))) short short8;
typedef __attribute__((ext_vector_type(4))) short short4v;
typedef __attribute__((ext_vector_type(4))) float f32x4;
typedef __attribute__((ext_vector_type(4))) unsigned int u32x4;

#define AS_GLOBAL __attribute__((address_space(1)))
#define AS_LDS __attribute__((address_space(3)))

static __device__ __forceinline__ short f2bf(float f) {
  return __builtin_bit_cast(short, __float2bfloat16(f));
}

extern "C" __global__ __launch_bounds__(256) void k_convert_w(
    const float* __restrict__ W, short* __restrict__ W2) {
  const int t = blockIdx.x * 256 + threadIdx.x;  // 16384 threads
  const int row = t >> 6, kb = t & 63;
  const float* src = W + row * IND + kb * 8;
  f32x4 x0 = *(const f32x4*)src;
  f32x4 x1 = *(const f32x4*)(src + 4);
  short8 o;
  o[0] = f2bf(x0[0]); o[1] = f2bf(x0[1]); o[2] = f2bf(x0[2]); o[3] = f2bf(x0[3]);
  o[4] = f2bf(x1[0]); o[5] = f2bf(x1[1]); o[6] = f2bf(x1[2]); o[7] = f2bf(x1[3]);
  *(short8*)(W2 + (size_t)kb * 2048 + row * 8) = o;
}

// Fused mask-conversion + Wh GEMM. 1152 blocks x 256 thr.
extern "C" __global__ __launch_bounds__(256, 2) void k_front(
    const int* __restrict__ mask, uint32_t* __restrict__ bm,
    const float* __restrict__ nodes, const short* __restrict__ W2,
    const float* __restrict__ Wb, const float* __restrict__ a1w,
    const float* __restrict__ a1b, const float* __restrict__ a2w,
    const float* __restrict__ a2b, short* __restrict__ WhL,
    float* __restrict__ sAC, uint32_t* __restrict__ sPK) {
  const int bid = blockIdx.x;
  const int tid = threadIdx.x;
  const int wv = tid >> 6, lane = tid & 63;

  if (bid % 9 != 8) {
    // ---- mask part: int32 -> bitmask, pure coalesced streaming ----
    const int mb = (bid / 9) * 8 + (bid % 9);  // [0,1024)
    const int gw = mb * 4 + wv;                // 4096 waves
    const size_t base = (size_t)gw * 16384;    // 64 iters x 256 ints
#pragma unroll 4
    for (int it = 0; it < 64; ++it) {
      const size_t ib = base + (size_t)it * 256;
      unsigned long long b0 = __ballot(mask[ib + lane] != 0);
      unsigned long long b1 = __ballot(mask[ib + 64 + lane] != 0);
      unsigned long long b2 = __ballot(mask[ib + 128 + lane] != 0);
      unsigned long long b3 = __ballot(mask[ib + 192 + lane] != 0);
      if (lane < 8) {
        unsigned long long s01 = (lane & 2) ? b1 : b0;
        unsigned long long s23 = (lane & 2) ? b3 : b2;
        unsigned long long sel = (lane & 4) ? s23 : s01;
        bm[ib / 32 + lane] = (uint32_t)(sel >> ((lane & 1) * 32));
      }
    }
    return;
  }

  // ---- wh part: Wh = nodes@W^T + b, 4 waves x 16 rows = 64 rows/block ----
  const int wb = bid / 9;  // [0,128)
  const int g = lane >> 4, m = lane & 15;
  const int rowbase = wb * 64 + wv * 16;

  f32x4 acc[16];
#pragma unroll
  for (int nf = 0; nf < 16; ++nf) acc[nf] = (f32x4){0.f, 0.f, 0.f, 0.f};

  const float* arow = nodes + (size_t)(rowbase + m) * IND;
  const short* bb = W2 + (size_t)g * 2048 + m * 8;
#pragma unroll 4
  for (int k0 = 0; k0 < IND; k0 += 32) {
    const float* ap = arow + k0 + g * 8;
    f32x4 x0 = *(const f32x4*)ap;
    f32x4 x1 = *(const f32x4*)(ap + 4);
    short8 af;
    af[0] = f2bf(x0[0]); af[1] = f2bf(x0[1]); af[2] = f2bf(x0[2]); af[3] = f2bf(x0[3]);
    af[4] = f2bf(x1[0]); af[5] = f2bf(x1[1]); af[6] = f2bf(x1[2]); af[7] = f2bf(x1[3]);
    const short* bk = bb + (size_t)(k0 >> 3) * 2048;
#pragma unroll
    for (int nf = 0; nf < 16; ++nf) {
      short8 bf = *(const short8*)(bk + nf * 128);
      acc[nf] = __builtin_amdgcn_mfma_f32_16x16x32_bf16(af, bf, acc[nf], 0, 0, 0);
    }
  }

  float p1[4] = {0.f, 0.f, 0.f, 0.f}, p2[4] = {0.f, 0.f, 0.f, 0.f};
#pragma unroll
  for (int nf = 0; nf < 16; ++nf) {
    const int n = nf * 16 + m;
    const float b = Wb[n], c1 = a1w[n], c2 = a2w[n];
#pragma unroll
    for (int r = 0; r < 4; ++r) {
      float v = acc[nf][r] + b;
      acc[nf][r] = v;
      p1[r] += c1 * v;
      p2[r] += c2 * v;
    }
  }
#pragma unroll
  for (int off = 1; off < 16; off <<= 1) {
#pragma unroll
    for (int r = 0; r < 4; ++r) {
      p1[r] += __shfl_xor(p1[r], off);
      p2[r] += __shfl_xor(p2[r], off);
    }
  }
  if (m == 0) {
    const float b1 = a1b[0], b2 = a2b[0];
#pragma unroll
    for (int r = 0; r < 4; ++r) {
      const int row = rowbase + g * 4 + r;
      const float v1 = p1[r] + b1, v2 = p2[r] + b2;
      sAC[row] = __expf(v1);             // A = e^{s1}
      sAC[NN + row] = __expf(0.2f * v1); // C = e^{0.2 s1}
      const float B = __expf(v2), D = __expf(0.2f * v2);
      sPK[row] = ((uint32_t)(uint16_t)f2bf(B) << 16) | (uint16_t)f2bf(D);
    }
  }

  const size_t cbase = ((size_t)(rowbase >> 3) + (g >> 1)) * 2048 + (g & 1) * 4;
#pragma unroll
  for (int nf = 0; nf < 16; ++nf) {
    short4v o;
#pragma unroll
    for (int r = 0; r < 4; ++r) o[r] = f2bf(acc[nf][r]);
    *(short4v*)(WhL + cbase + (size_t)(nf * 16 + m) * 8) = o;
  }
}

extern "C" __global__ __launch_bounds__(512, 4) void k_attn(
    const uint32_t* __restrict__ bm, const short* __restrict__ WhL,
    const float* __restrict__ sAC, const uint32_t* __restrict__ sPK,
    float* __restrict__ pnum, float* __restrict__ pden) {
  const int tid = threadIdx.x;
  const int w = tid >> 6, lane = tid & 63, g = lane >> 4, m = lane & 15;
  const int rt = blockIdx.x >> 3, jc = blockIdx.x & 7;
  const int rg = w & 1, ns = w >> 1;   // 2 rowgroups(32) x 4 colquarters(64)
  const int rb = rt * 64 + rg * 32;

  const float A0 = sAC[rb + m],      A1 = sAC[rb + 16 + m];
  const float C0 = sAC[NN + rb + m], C1 = sAC[NN + rb + 16 + m];

  f32x4 acc0[4], acc1[4];
#pragma unroll
  for (int nf = 0; nf < 4; ++nf) {
    acc0[nf] = (f32x4){0.f, 0.f, 0.f, 0.f};
    acc1[nf] = (f32x4){0.f, 0.f, 0.f, 0.f};
  }
  float den0 = 0.f, den1 = 0.f;

  // per-lane bases
  const uint32_t* bw0 = bm + (size_t)(rb + m) * 256 + jc * 32;
  const uint32_t* bw1 = bw0 + (size_t)16 * 256;
  // B-frag: chunk (v*4+g), col n = ns*64 + nf*16 + m -> one 16B load each
  const short* gB = WhL + (size_t)jc * 262144 + (size_t)g * 2048 +
                    (ns * 64 + m) * 8;
  const uint32_t* gP = sPK + (size_t)jc * 1024 + g * 8;

  struct Win {  // one j-window's operands: EXACTLY 8 loads
    short8 b0, b1, b2, b3;
    u32x4 q0, q1;
    uint32_t c0, c1;
  };

  auto issue = [&](int v, Win& W_) {
    const short* p = gB + (size_t)v * 8192;
    W_.b0 = *(const short8*)(p);
    W_.b1 = *(const short8*)(p + 128);
    W_.b2 = *(const short8*)(p + 256);
    W_.b3 = *(const short8*)(p + 384);
    const uint32_t* pp = gP + v * 32;
    W_.q0 = *(const u32x4*)(pp);
    W_.q1 = *(const u32x4*)(pp + 4);
    W_.c0 = bw0[v];
    W_.c1 = bw1[v];
  };

  // exp-free, branch-free build: val = max(A*B, C*D) == exp(lrelu(s1+s2))
  auto build = [&](float A, float C, uint32_t mbits,
                   const u32x4& q0, const u32x4& q1, float& den) -> short8 {
    short8 af;
#pragma unroll
    for (int i = 0; i < 8; ++i) {
      const uint32_t pw = (i < 4) ? q0[i] : q1[i - 4];
      const float D = __builtin_bit_cast(float, pw << 16);
      const float B = __builtin_bit_cast(float, pw & 0xFFFF0000u);
      const float val = fmaxf(A * B, C * D);
      const float pv = ((mbits >> i) & 1u) ? val : 0.f;
      den += pv;
      af[i] = f2bf(pv);
    }
    return af;
  };

  auto compute = [&](const Win& W_) {
    short8 af0 = build(A0, C0, W_.c0 >> (g * 8), W_.q0, W_.q1, den0);
    short8 af1 = build(A1, C1, W_.c1 >> (g * 8), W_.q0, W_.q1, den1);
    __builtin_amdgcn_s_setprio(1);
    acc0[0] = __builtin_amdgcn_mfma_f32_16x16x32_bf16(af0, W_.b0, acc0[0], 0, 0, 0);
    acc1[0] = __builtin_amdgcn_mfma_f32_16x16x32_bf16(af1, W_.b0, acc1[0], 0, 0, 0);
    acc0[1] = __builtin_amdgcn_mfma_f32_16x16x32_bf16(af0, W_.b1, acc0[1], 0, 0, 0);
    acc1[1] = __builtin_amdgcn_mfma_f32_16x16x32_bf16(af1, W_.b1, acc1[1], 0, 0, 0);
    acc0[2] = __builtin_amdgcn_mfma_f32_16x16x32_bf16(af0, W_.b2, acc0[2], 0, 0, 0);
    acc1[2] = __builtin_amdgcn_mfma_f32_16x16x32_bf16(af1, W_.b2, acc1[2], 0, 0, 0);
    acc0[3] = __builtin_amdgcn_mfma_f32_16x16x32_bf16(af0, W_.b3, acc0[3], 0, 0, 0);
    acc1[3] = __builtin_amdgcn_mfma_f32_16x16x32_bf16(af1, W_.b3, acc1[3], 0, 0, 0);
    __builtin_amdgcn_s_setprio(0);
  };

  // ---- wave-private pipeline: no LDS, no barriers; vmcnt(8) never 0 ----
  Win WA, WB;
  issue(0, WA);
  issue(1, WB);
  for (int u = 0; u < 32; u += 2) {
    // outstanding: [older-window 8, newer-window 8] -> vmcnt(8) drains older
    asm volatile("s_waitcnt vmcnt(8)" ::: "memory");
    __builtin_amdgcn_sched_barrier(0);
    compute(WA);
    issue((u + 2 < 32) ? u + 2 : 31, WA);   // clamped re-issue: dead, uniform
    asm volatile("s_waitcnt vmcnt(8)" ::: "memory");
    __builtin_amdgcn_sched_barrier(0);
    compute(WB);
    issue((u + 3 < 32) ? u + 3 : 31, WB);
  }

  // den reduce across the 4 k-groups: lanes end with den for their rows
  den0 += __shfl_xor(den0, 16); den0 += __shfl_xor(den0, 32);
  den1 += __shfl_xor(den1, 16); den1 += __shfl_xor(den1, 32);
  if (ns == 0 && lane < 16) {
    pden[jc * NN + rb + m] = den0;
    pden[jc * NN + rb + 16 + m] = den1;
  }

  // each wave owns its disjoint 32x64 tile of pnum[jc]
  float* pn = pnum + (size_t)jc * NN * OUTD + (size_t)rb * OUTD + ns * 64;
#pragma unroll
  for (int r = 0; r < 4; ++r) {
    const int q = g * 4 + r;
#pragma unroll
    for (int nf = 0; nf < 4; ++nf) {
      pn[(size_t)q * OUTD + nf * 16 + m] = acc0[nf][r];
      pn[(size_t)(16 + q) * OUTD + nf * 16 + m] = acc1[nf][r];
    }
  }
}

extern "C" __global__ __launch_bounds__(256) void k_comb(
    const float* __restrict__ pnum, const float* __restrict__ pden,
    float* __restrict__ out) {
  const int idx = blockIdx.x * 256 + threadIdx.x;  // 524288 threads
  const int row = idx >> 6, c4 = (idx & 63) * 4;
  f32x4 s = (f32x4){0.f, 0.f, 0.f, 0.f};
  float d = 0.f;
#pragma unroll
  for (int jc = 0; jc < 8; ++jc) {
    f32x4 v = *(const f32x4*)(pnum + ((size_t)jc * NN + row) * OUTD + c4);
    s += v;
    d += pden[jc * NN + row];
  }
  const float inv = 1.f / d;
  *(f32x4*)(out + (size_t)row * OUTD + c4) = s * inv;
}

extern "C" void kernel_launch(void* const* d_in, const int* in_sizes, int n_in,
                              void* d_out, int out_size, void* d_ws, size_t ws_size,
                              hipStream_t stream) {
  const float* nodes = (const float*)d_in[0];
  const int*   mask  = (const int*)d_in[1];
  const float* W_w   = (const float*)d_in[2];
  const float* W_b   = (const float*)d_in[3];
  const float* a1w   = (const float*)d_in[4];
  const float* a1b   = (const float*)d_in[5];
  const float* a2w   = (const float*)d_in[6];
  const float* a2b   = (const float*)d_in[7];
  float* out = (float*)d_out;

  char* ws = (char*)d_ws;
  short*    WhL  = (short*)(ws);                                    // 4 MiB
  short*    W2   = (short*)(ws + (size_t)4  * 1024 * 1024 + 65536); // 256 KiB
  uint32_t* bmp  = (uint32_t*)(ws + (size_t)5  * 1024 * 1024);      // 8 MiB
  float*    sAC  = (float*)(ws + (size_t)13 * 1024 * 1024);         // 64 KiB
  uint32_t* sPK  = (uint32_t*)(ws + (size_t)14 * 1024 * 1024);      // 32 KiB
  float*    pnum = (float*)(ws + (size_t)16 * 1024 * 1024);         // 64 MiB
  float*    pden = (float*)(ws + (size_t)96 * 1024 * 1024);         // 256 KiB

  hipLaunchKernelGGL(k_convert_w, dim3(64), dim3(256), 0, stream, W_w, W2);
  hipLaunchKernelGGL(k_front, dim3(1152), dim3(256), 0, stream,
                     mask, bmp, nodes, W2, W_b, a1w, a1b, a2w, a2b,
                     WhL, sAC, sPK);
  hipLaunchKernelGGL(k_attn, dim3(1024), dim3(512), 0, stream,
                     bmp, WhL, sAC, sPK, pnum, pden);
  hipLaunchKernelGGL(k_comb, dim3(2048), dim3(256), 0, stream,
                     pnum, pden, out);
}

// Round 20
// 253.868 us; speedup vs baseline: 1.9367x; 1.9367x over previous
//
#include <hip/hip_runtime.h>
#include <hip/hip_bf16.h>
#include <stdint.h>

// DenseGraphAttentionHead N=8192, IN=512, OUT=256, ~50% dense int32 mask.
//
// Pipeline:
//   k_convert_w : W f32 -> bf16 chunked (16B chunk (kb,row) at kb*2048+row*8).
//   k_front     : FUSED k_mask + k_wh (bid%9==8 -> wh). mask: int32 ->
//                 bitmask bm[row][wj] via __ballot (coalesced stream). wh:
//                 Wh = nodes@W^T + b (mfma) -> WhL chunked bf16 + tables.
//                 MAX-IDENTITY (exact): exp(lrelu(s1+s2)) = max(e^{s1}e^{s2},
//                 e^{.2s1}e^{.2s2}).
//                 sAC = [A=e^{s1} | C=e^{.2s1}] f32;
//                 sPK[j] = u32 {bf16 B=e^{s2} hi | bf16 D=e^{.2s2} lo}.
//   k_attn      : FREE-RUNNING waves + WAVE-PRIVATE LDS double-buffer.
//                 No s_barrier anywhere (wave-slip hides latency - forbidden
//                 in all barrier'd designs R6-R18 ~100us); no reg-staged
//                 B-frags (R19's spill - B goes via global_load_lds at zero
//                 VGPR cost). Wave = 32 rows x 64 cols (acc 32), block =
//                 8 waves = 2 rg x 4 ns, grid 128rt x 8jc = 1024 blocks =
//                 2/CU, 16 waves/CU. Per window 8 VMEM: 4 gload_lds (4KB
//                 B-slice -> private buf) + 2 PK + 2 bm (ping-pong regs).
//                 Loop: vmcnt(8) -> compute {4x ds_read_b128 (conflict-free),
//                 build, 8 MFMA} -> lgkmcnt(0) -> issue u+2 into buf[u&1].
//   k_comb      : out = sum_jc(pnum) / sum_jc(pden), 8 partials.
//
// MFMA conventions (verified R1-R19 on this problem):
//   A frag: lane&15 = m, k = (lane>>4)*8 + i ; B same per-lane k order
//   D: col = lane&15, row = (lane>>4)*4 + reg

#define NN 8192
#define IND 512
#define OUTD 256

typedef __attribute__((ext_vector_type(8))) short short8;
typedef __attribute__((ext_vector_type(4))) short short4v;
typedef __attribute__((ext_vector_type(4))) float f32x4;
typedef __attribute__((ext_vector_type(4))) unsigned int u32x4;

#define AS_GLOBAL __attribute__((address_space(1)))
#define AS_LDS __attribute__((address_space(3)))

static __device__ __forceinline__ short f2bf(float f) {
  return __builtin_bit_cast(short, __float2bfloat16(f));
}

extern "C" __global__ __launch_bounds__(256) void k_convert_w(
    const float* __restrict__ W, short* __restrict__ W2) {
  const int t = blockIdx.x * 256 + threadIdx.x;  // 16384 threads
  const int row = t >> 6, kb = t & 63;
  const float* src = W + row * IND + kb * 8;
  f32x4 x0 = *(const f32x4*)src;
  f32x4 x1 = *(const f32x4*)(src + 4);
  short8 o;
  o[0] = f2bf(x0[0]); o[1] = f2bf(x0[1]); o[2] = f2bf(x0[2]); o[3] = f2bf(x0[3]);
  o[4] = f2bf(x1[0]); o[5] = f2bf(x1[1]); o[6] = f2bf(x1[2]); o[7] = f2bf(x1[3]);
  *(short8*)(W2 + (size_t)kb * 2048 + row * 8) = o;
}

// Fused mask-conversion + Wh GEMM. 1152 blocks x 256 thr.
extern "C" __global__ __launch_bounds__(256, 2) void k_front(
    const int* __restrict__ mask, uint32_t* __restrict__ bm,
    const float* __restrict__ nodes, const short* __restrict__ W2,
    const float* __restrict__ Wb, const float* __restrict__ a1w,
    const float* __restrict__ a1b, const float* __restrict__ a2w,
    const float* __restrict__ a2b, short* __restrict__ WhL,
    float* __restrict__ sAC, uint32_t* __restrict__ sPK) {
  const int bid = blockIdx.x;
  const int tid = threadIdx.x;
  const int wv = tid >> 6, lane = tid & 63;

  if (bid % 9 != 8) {
    // ---- mask part: int32 -> bitmask, pure coalesced streaming ----
    const int mb = (bid / 9) * 8 + (bid % 9);  // [0,1024)
    const int gw = mb * 4 + wv;                // 4096 waves
    const size_t base = (size_t)gw * 16384;    // 64 iters x 256 ints
#pragma unroll 4
    for (int it = 0; it < 64; ++it) {
      const size_t ib = base + (size_t)it * 256;
      unsigned long long b0 = __ballot(mask[ib + lane] != 0);
      unsigned long long b1 = __ballot(mask[ib + 64 + lane] != 0);
      unsigned long long b2 = __ballot(mask[ib + 128 + lane] != 0);
      unsigned long long b3 = __ballot(mask[ib + 192 + lane] != 0);
      if (lane < 8) {
        unsigned long long s01 = (lane & 2) ? b1 : b0;
        unsigned long long s23 = (lane & 2) ? b3 : b2;
        unsigned long long sel = (lane & 4) ? s23 : s01;
        bm[ib / 32 + lane] = (uint32_t)(sel >> ((lane & 1) * 32));
      }
    }
    return;
  }

  // ---- wh part: Wh = nodes@W^T + b, 4 waves x 16 rows = 64 rows/block ----
  const int wb = bid / 9;  // [0,128)
  const int g = lane >> 4, m = lane & 15;
  const int rowbase = wb * 64 + wv * 16;

  f32x4 acc[16];
#pragma unroll
  for (int nf = 0; nf < 16; ++nf) acc[nf] = (f32x4){0.f, 0.f, 0.f, 0.f};

  const float* arow = nodes + (size_t)(rowbase + m) * IND;
  const short* bb = W2 + (size_t)g * 2048 + m * 8;
#pragma unroll 4
  for (int k0 = 0; k0 < IND; k0 += 32) {
    const float* ap = arow + k0 + g * 8;
    f32x4 x0 = *(const f32x4*)ap;
    f32x4 x1 = *(const f32x4*)(ap + 4);
    short8 af;
    af[0] = f2bf(x0[0]); af[1] = f2bf(x0[1]); af[2] = f2bf(x0[2]); af[3] = f2bf(x0[3]);
    af[4] = f2bf(x1[0]); af[5] = f2bf(x1[1]); af[6] = f2bf(x1[2]); af[7] = f2bf(x1[3]);
    const short* bk = bb + (size_t)(k0 >> 3) * 2048;
#pragma unroll
    for (int nf = 0; nf < 16; ++nf) {
      short8 bf = *(const short8*)(bk + nf * 128);
      acc[nf] = __builtin_amdgcn_mfma_f32_16x16x32_bf16(af, bf, acc[nf], 0, 0, 0);
    }
  }

  float p1[4] = {0.f, 0.f, 0.f, 0.f}, p2[4] = {0.f, 0.f, 0.f, 0.f};
#pragma unroll
  for (int nf = 0; nf < 16; ++nf) {
    const int n = nf * 16 + m;
    const float b = Wb[n], c1 = a1w[n], c2 = a2w[n];
#pragma unroll
    for (int r = 0; r < 4; ++r) {
      float v = acc[nf][r] + b;
      acc[nf][r] = v;
      p1[r] += c1 * v;
      p2[r] += c2 * v;
    }
  }
#pragma unroll
  for (int off = 1; off < 16; off <<= 1) {
#pragma unroll
    for (int r = 0; r < 4; ++r) {
      p1[r] += __shfl_xor(p1[r], off);
      p2[r] += __shfl_xor(p2[r], off);
    }
  }
  if (m == 0) {
    const float b1 = a1b[0], b2 = a2b[0];
#pragma unroll
    for (int r = 0; r < 4; ++r) {
      const int row = rowbase + g * 4 + r;
      const float v1 = p1[r] + b1, v2 = p2[r] + b2;
      sAC[row] = __expf(v1);             // A = e^{s1}
      sAC[NN + row] = __expf(0.2f * v1); // C = e^{0.2 s1}
      const float B = __expf(v2), D = __expf(0.2f * v2);
      sPK[row] = ((uint32_t)(uint16_t)f2bf(B) << 16) | (uint16_t)f2bf(D);
    }
  }

  const size_t cbase = ((size_t)(rowbase >> 3) + (g >> 1)) * 2048 + (g & 1) * 4;
#pragma unroll
  for (int nf = 0; nf < 16; ++nf) {
    short4v o;
#pragma unroll
    for (int r = 0; r < 4; ++r) o[r] = f2bf(acc[nf][r]);
    *(short4v*)(WhL + cbase + (size_t)(nf * 16 + m) * 8) = o;
  }
}

extern "C" __global__ __launch_bounds__(512, 4) void k_attn(
    const uint32_t* __restrict__ bm, const short* __restrict__ WhL,
    const float* __restrict__ sAC, const uint32_t* __restrict__ sPK,
    float* __restrict__ pnum, float* __restrict__ pden) {
  // Wave-private LDS: wave w owns [w*8192, w*8192+8192): 2 x 4 KB buffers.
  // Buffer layout (bytes): c*1024 + col*16, c = j-octet 0..3, col 0..63.
  __shared__ char smem[65536];

  const int tid = threadIdx.x;
  const int w = tid >> 6, lane = tid & 63, g = lane >> 4, m = lane & 15;
  const int rt = blockIdx.x >> 3, jc = blockIdx.x & 7;
  const int rg = w & 1, ns = w >> 1;   // 2 rowgroups(32) x 4 colquarters(64)
  const int rb = rt * 64 + rg * 32;

  const float A0 = sAC[rb + m],      A1 = sAC[rb + 16 + m];
  const float C0 = sAC[NN + rb + m], C1 = sAC[NN + rb + 16 + m];

  f32x4 acc0[4], acc1[4];
#pragma unroll
  for (int nf = 0; nf < 4; ++nf) {
    acc0[nf] = (f32x4){0.f, 0.f, 0.f, 0.f};
    acc1[nf] = (f32x4){0.f, 0.f, 0.f, 0.f};
  }
  float den0 = 0.f, den1 = 0.f;

  // per-lane bases
  const uint32_t* bw0 = bm + (size_t)(rb + m) * 256 + jc * 32;
  const uint32_t* bw1 = bw0 + (size_t)16 * 256;
  // staging source: chunk (v*4+c), cols [ns*64, ns*64+64), lane = col
  const short* gB = WhL + (size_t)jc * 262144 + (ns * 64 + lane) * 8;
  const uint32_t* gP = sPK + (size_t)jc * 1024 + g * 8;
  char* myb = smem + w * 8192;

  // issue window v's 8 VMEM ops: 4 gload_lds -> buf bi, 2 PK + 2 bm -> regs
  auto issue = [&](int v, int bi, u32x4& q0, u32x4& q1,
                   uint32_t& c0, uint32_t& c1) {
    const short* p = gB + (size_t)v * 8192;
    char* dst = myb + bi * 4096 + lane * 16;
#pragma unroll
    for (int c = 0; c < 4; ++c) {
      __builtin_amdgcn_global_load_lds(
          (const AS_GLOBAL void*)(p + c * 2048),
          (AS_LDS void*)(dst + c * 1024), 16, 0, 0);
    }
    const uint32_t* pp = gP + v * 32;
    q0 = *(const u32x4*)(pp);
    q1 = *(const u32x4*)(pp + 4);
    c0 = bw0[v];
    c1 = bw1[v];
  };

  // exp-free, branch-free build: val = max(A*B, C*D) == exp(lrelu(s1+s2))
  auto build = [&](float A, float C, uint32_t mbits,
                   const u32x4& q0, const u32x4& q1, float& den) -> short8 {
    short8 af;
#pragma unroll
    for (int i = 0; i < 8; ++i) {
      const uint32_t pw = (i < 4) ? q0[i] : q1[i - 4];
      const float D = __builtin_bit_cast(float, pw << 16);
      const float B = __builtin_bit_cast(float, pw & 0xFFFF0000u);
      const float val = fmaxf(A * B, C * D);
      const float pv = ((mbits >> i) & 1u) ? val : 0.f;
      den += pv;
      af[i] = f2bf(pv);
    }
    return af;
  };

  // compute window from buf bi: 4 ds_read_b128 B-frags, 2 builds, 8 MFMA
  auto compute = [&](int bi, const u32x4& q0, const u32x4& q1,
                     uint32_t c0, uint32_t c1) {
    short8 af0 = build(A0, C0, c0 >> (g * 8), q0, q1, den0);
    short8 af1 = build(A1, C1, c1 >> (g * 8), q0, q1, den1);
    const char* bl = myb + bi * 4096 + g * 1024 + m * 16;
    short8 b0 = *(const short8*)(bl);
    short8 b1 = *(const short8*)(bl + 256);
    short8 b2 = *(const short8*)(bl + 512);
    short8 b3 = *(const short8*)(bl + 768);
    __builtin_amdgcn_s_setprio(1);
    acc0[0] = __builtin_amdgcn_mfma_f32_16x16x32_bf16(af0, b0, acc0[0], 0, 0, 0);
    acc1[0] = __builtin_amdgcn_mfma_f32_16x16x32_bf16(af1, b0, acc1[0], 0, 0, 0);
    acc0[1] = __builtin_amdgcn_mfma_f32_16x16x32_bf16(af0, b1, acc0[1], 0, 0, 0);
    acc1[1] = __builtin_amdgcn_mfma_f32_16x16x32_bf16(af1, b1, acc1[1], 0, 0, 0);
    acc0[2] = __builtin_amdgcn_mfma_f32_16x16x32_bf16(af0, b2, acc0[2], 0, 0, 0);
    acc1[2] = __builtin_amdgcn_mfma_f32_16x16x32_bf16(af1, b2, acc1[2], 0, 0, 0);
    acc0[3] = __builtin_amdgcn_mfma_f32_16x16x32_bf16(af0, b3, acc0[3], 0, 0, 0);
    acc1[3] = __builtin_amdgcn_mfma_f32_16x16x32_bf16(af1, b3, acc1[3], 0, 0, 0);
    __builtin_amdgcn_s_setprio(0);
  };

  // ---- free-running pipeline: NO barriers; vmcnt(8) never 0 ----
  u32x4 qA0, qA1, qB0, qB1;
  uint32_t cA0, cA1, cB0, cB1;
  issue(0, 0, qA0, qA1, cA0, cA1);
  issue(1, 1, qB0, qB1, cB0, cB1);
  for (int u = 0; u < 32; u += 2) {
    // drain window u's 8 ops (8 newer from window u+1 stay in flight)
    asm volatile("s_waitcnt vmcnt(8)" ::: "memory");
    __builtin_amdgcn_sched_barrier(0);
    compute(0, qA0, qA1, cA0, cA1);
    // own ds_reads of buf0 retired before overwriting it
    asm volatile("s_waitcnt lgkmcnt(0)" ::: "memory");
    __builtin_amdgcn_sched_barrier(0);
    issue((u + 2 < 32) ? u + 2 : 31, 0, qA0, qA1, cA0, cA1);

    asm volatile("s_waitcnt vmcnt(8)" ::: "memory");
    __builtin_amdgcn_sched_barrier(0);
    compute(1, qB0, qB1, cB0, cB1);
    asm volatile("s_waitcnt lgkmcnt(0)" ::: "memory");
    __builtin_amdgcn_sched_barrier(0);
    issue((u + 3 < 32) ? u + 3 : 31, 1, qB0, qB1, cB0, cB1);
  }

  // den reduce across the 4 k-groups: lanes end with den for their rows
  den0 += __shfl_xor(den0, 16); den0 += __shfl_xor(den0, 32);
  den1 += __shfl_xor(den1, 16); den1 += __shfl_xor(den1, 32);
  if (ns == 0 && lane < 16) {
    pden[jc * NN + rb + m] = den0;
    pden[jc * NN + rb + 16 + m] = den1;
  }

  // each wave owns its disjoint 32x64 tile of pnum[jc]
  float* pn = pnum + (size_t)jc * NN * OUTD + (size_t)rb * OUTD + ns * 64;
#pragma unroll
  for (int r = 0; r < 4; ++r) {
    const int q = g * 4 + r;
#pragma unroll
    for (int nf = 0; nf < 4; ++nf) {
      pn[(size_t)q * OUTD + nf * 16 + m] = acc0[nf][r];
      pn[(size_t)(16 + q) * OUTD + nf * 16 + m] = acc1[nf][r];
    }
  }
}

extern "C" __global__ __launch_bounds__(256) void k_comb(
    const float* __restrict__ pnum, const float* __restrict__ pden,
    float* __restrict__ out) {
  const int idx = blockIdx.x * 256 + threadIdx.x;  // 524288 threads
  const int row = idx >> 6, c4 = (idx & 63) * 4;
  f32x4 s = (f32x4){0.f, 0.f, 0.f, 0.f};
  float d = 0.f;
#pragma unroll
  for (int jc = 0; jc < 8; ++jc) {
    f32x4 v = *(const f32x4*)(pnum + ((size_t)jc * NN + row) * OUTD + c4);
    s += v;
    d += pden[jc * NN + row];
  }
  const float inv = 1.f / d;
  *(f32x4*)(out + (size_t)row * OUTD + c4) = s * inv;
}

extern "C" void kernel_launch(void* const* d_in, const int* in_sizes, int n_in,
                              void* d_out, int out_size, void* d_ws, size_t ws_size,
                              hipStream_t stream) {
  const float* nodes = (const float*)d_in[0];
  const int*   mask  = (const int*)d_in[1];
  const float* W_w   = (const float*)d_in[2];
  const float* W_b   = (const float*)d_in[3];
  const float* a1w   = (const float*)d_in[4];
  const float* a1b   = (const float*)d_in[5];
  const float* a2w   = (const float*)d_in[6];
  const float* a2b   = (const float*)d_in[7];
  float* out = (float*)d_out;

  char* ws = (char*)d_ws;
  short*    WhL  = (short*)(ws);                                    // 4 MiB
  short*    W2   = (short*)(ws + (size_t)4  * 1024 * 1024 + 65536); // 256 KiB
  uint32_t* bmp  = (uint32_t*)(ws + (size_t)5  * 1024 * 1024);      // 8 MiB
  float*    sAC  = (float*)(ws + (size_t)13 * 1024 * 1024);         // 64 KiB
  uint32_t* sPK  = (uint32_t*)(ws + (size_t)14 * 1024 * 1024);      // 32 KiB
  float*    pnum = (float*)(ws + (size_t)16 * 1024 * 1024);         // 64 MiB
  float*    pden = (float*)(ws + (size_t)96 * 1024 * 1024);         // 256 KiB

  hipLaunchKernelGGL(k_convert_w, dim3(64), dim3(256), 0, stream, W_w, W2);
  hipLaunchKernelGGL(k_front, dim3(1152), dim3(256), 0, stream,
                     mask, bmp, nodes, W2, W_b, a1w, a1b, a2w, a2b,
                     WhL, sAC, sPK);
  hipLaunchKernelGGL(k_attn, dim3(1024), dim3(512), 0, stream,
                     bmp, WhL, sAC, sPK, pnum, pden);
  hipLaunchKernelGGL(k_comb, dim3(2048), dim3(256), 0, stream,
                     pnum, pden, out);
}